// Round 6
// baseline (38.398 us; speedup 1.0000x reference)
//
#include <hip/hip_runtime.h>

#define N_KPTS 10
#define BS 8
#define HH 180
#define WW 240
#define HW (HH * WW)
#define NPIX (BS * HW)
#define NQ (NPIX / 4)                       // 86400 pixel-quads
#define COEFFS_SIZE (BS * (N_KPTS + 1) * HW)

typedef float f32x4 __attribute__((ext_vector_type(4)));

static __device__ __forceinline__ f32x4 splat4(float x) { return (f32x4){x, x, x, x}; }
static __device__ __forceinline__ f32x4 vfma4(f32x4 a, f32x4 b, f32x4 c) {
    f32x4 r;
    r.x = fmaf(a.x, b.x, c.x);
    r.y = fmaf(a.y, b.y, c.y);
    r.z = fmaf(a.z, b.z, c.z);
    r.w = fmaf(a.w, b.w, c.w);
    return r;
}

// 2 threads per pixel-quad ("plane-split"): both compute the full Lagrange
// algebra for their 4 pixels (compute is cheap, ~26% VALU), each writes only
// half the 121 output planes with 16B/lane stores. Halves live in separate
// waves (waves 0,1 = half 0; waves 2,3 = half 1) so every store instruction
// is 64-lane dense -> 1KB contiguous. Grid = 675 blocks x 256 = 2700 waves,
// same occupancy shape as the 8B/lane version, but m13-style 16B access.
__global__ __launch_bounds__(256) void curve_integrator_kernel(
    const float* __restrict__ deriv,    // [BS][N_KPTS][HW]
    const float* __restrict__ blurry,   // [BS][1][HW]
    const float* __restrict__ kpts,     // [BS][N_KPTS][HW]
    float* __restrict__ out_coeffs,     // [BS][N_KPTS+1][HW]
    float* __restrict__ out_cache)      // [BS][N_KPTS][N_KPTS][HW]
{
    const int lane = threadIdx.x & 63;
    const int w    = threadIdx.x >> 6;          // wave in block, 0..3
    const int h    = w >> 1;                    // plane-half: waves 0,1 -> 0; 2,3 -> 1
    const int ql   = ((w & 1) << 6) | lane;     // 0..127 quad-local
    const int q    = blockIdx.x * 128 + ql;     // 675*128 = 86400 = NQ exactly
    const int p    = q * 4;                     // first pixel of quad
    const int b    = p / HW;                    // HW % 4 == 0 -> quad stays in plane
    const int hw   = p - b * HW;

    const float* kp_base    = kpts  + (size_t)b * N_KPTS * HW + hw;
    const float* d_base     = deriv + (size_t)b * N_KPTS * HW + hw;
    float*       cache_base = out_cache + (size_t)b * N_KPTS * N_KPTS * HW + hw;

    f32x4 kp[N_KPTS];
#pragma unroll
    for (int i = 0; i < N_KPTS; ++i)
        kp[i] = *(const f32x4*)(kp_base + (size_t)i * HW);

    f32x4 coeffs[N_KPTS];
#pragma unroll
    for (int o = 0; o < N_KPTS; ++o) coeffs[o] = splat4(0.0f);

    const float rcp_tab[N_KPTS] = {
        1.0f, 1.0f/2.0f, 1.0f/3.0f, 1.0f/4.0f, 1.0f/5.0f,
        1.0f/6.0f, 1.0f/7.0f, 1.0f/8.0f, 1.0f/9.0f, 1.0f/10.0f
    };

#pragma unroll
    for (int i = 0; i < N_KPTS; ++i) {
        // c[k] = coeff of x^k in prod_{j != i} (x - kp[j]); all indexing static
        f32x4 c[N_KPTS];
        c[0] = splat4(1.0f);
#pragma unroll
        for (int k = 1; k < N_KPTS; ++k) c[k] = splat4(0.0f);

        f32x4 denom = splat4(1.0f);
#pragma unroll
        for (int j = 0; j < N_KPTS; ++j) {
            if (j == i) continue;                  // elided at compile time
            f32x4 nkpj = -kp[j];
            denom = denom * (kp[i] - kp[j]);
#pragma unroll
            for (int k = N_KPTS - 1; k >= 1; --k)
                c[k] = vfma4(nkpj, c[k], c[k - 1]);
            c[0] = nkpj * c[0];
        }

        f32x4 inv = splat4(1.0f) / denom;
        f32x4 di  = *(const f32x4*)(d_base + (size_t)i * HW);
#pragma unroll
        for (int o = 0; o < N_KPTS; ++o) {
            f32x4 v = c[o] * (inv * splat4(rcp_tab[o]));
            // half 0 owns cache planes o<5, half 1 owns o>=5 (wave-uniform branch)
            if ((o < 5) == (h == 0))
                *(f32x4*)(cache_base + (size_t)(o * N_KPTS + i) * HW) = v;
            coeffs[o] = vfma4(v, di, coeffs[o]);
        }
    }

    float* oc = out_coeffs + (size_t)b * (N_KPTS + 1) * HW + hw;
    if (h == 0) {
        // integral over [-1,1]: odd o only: 2*coeffs[o]/(o+2)
        f32x4 integral = coeffs[1] * splat4(2.0f / 3.0f);
        integral = vfma4(coeffs[3], splat4(2.0f / 5.0f), integral);
        integral = vfma4(coeffs[5], splat4(2.0f / 7.0f), integral);
        integral = vfma4(coeffs[7], splat4(2.0f / 9.0f), integral);
        integral = vfma4(coeffs[9], splat4(2.0f / 11.0f), integral);

        f32x4 bl = *(const f32x4*)(blurry + (size_t)b * HW + hw);
        f32x4 baseline = (bl * splat4(2.0f) - integral) * splat4(0.5f);

        *(f32x4*)oc = baseline;                          // plane 0
#pragma unroll
        for (int o = 0; o < 5; ++o)                      // planes 1..5
            *(f32x4*)(oc + (size_t)(o + 1) * HW) = coeffs[o];
    } else {
#pragma unroll
        for (int o = 5; o < N_KPTS; ++o)                 // planes 6..10
            *(f32x4*)(oc + (size_t)(o + 1) * HW) = coeffs[o];
    }
}

extern "C" void kernel_launch(void* const* d_in, const int* in_sizes, int n_in,
                              void* d_out, int out_size, void* d_ws, size_t ws_size,
                              hipStream_t stream) {
    const float* deriv  = (const float*)d_in[0];
    const float* blurry = (const float*)d_in[1];
    const float* kpts   = (const float*)d_in[2];

    float* out_coeffs = (float*)d_out;                 // BS*(N_KPTS+1)*HW
    float* out_cache  = (float*)d_out + COEFFS_SIZE;   // BS*N_KPTS*N_KPTS*HW

    int threads = 256;
    int blocks  = (NQ * 2) / threads;                  // 675, exact
    curve_integrator_kernel<<<blocks, threads, 0, stream>>>(
        deriv, blurry, kpts, out_coeffs, out_cache);
}

// Round 7
// 34.992 us; speedup vs baseline: 1.0973x; 1.0973x over previous
//
#include <hip/hip_runtime.h>

#define N_KPTS 10
#define BS 8
#define HH 180
#define WW 240
#define HW (HH * WW)
#define NPIX (BS * HW)
#define COEFFS_SIZE (BS * (N_KPTS + 1) * HW)

typedef float f32x2 __attribute__((ext_vector_type(2)));

static __device__ __forceinline__ f32x2 splat2(float x) { return (f32x2){x, x}; }
static __device__ __forceinline__ f32x2 vfma2(f32x2 a, f32x2 b, f32x2 c) {
    f32x2 r;
    r.x = fmaf(a.x, b.x, c.x);
    r.y = fmaf(a.y, b.y, c.y);
    return r;
}

// Plane-split at f32x2: two wave-uniform halves per pixel-pair. Both halves
// run the full Lagrange algebra on their 2 pixels (VALU is cheap, ~33% busy
// duplicated); half 0 stores cache planes o<5 + coeffs planes 0-5, half 1
// stores cache o>=5 + coeffs planes 6-10. Doubles the grid to 5400 waves
// (5.3/SIMD) for latency hiding / store smoothing while keeping every store
// 64-lane x 8B = 512B contiguous. Unused accumulators in half 1 are DCE'd
// (all indexing static).
template <int H>
static __device__ __forceinline__ void curve_body(
    int b, int hw,
    const float* __restrict__ deriv, const float* __restrict__ blurry,
    const float* __restrict__ kpts, float* __restrict__ out_coeffs,
    float* __restrict__ out_cache)
{
    const float* kp_base    = kpts  + (size_t)b * N_KPTS * HW + hw;
    const float* d_base     = deriv + (size_t)b * N_KPTS * HW + hw;
    float*       cache_base = out_cache + (size_t)b * N_KPTS * N_KPTS * HW + hw;

    f32x2 kp[N_KPTS];
#pragma unroll
    for (int i = 0; i < N_KPTS; ++i)
        kp[i] = *(const f32x2*)(kp_base + (size_t)i * HW);

    f32x2 coeffs[N_KPTS];
#pragma unroll
    for (int o = 0; o < N_KPTS; ++o) coeffs[o] = splat2(0.0f);

    const float rcp_tab[N_KPTS] = {
        1.0f, 1.0f/2.0f, 1.0f/3.0f, 1.0f/4.0f, 1.0f/5.0f,
        1.0f/6.0f, 1.0f/7.0f, 1.0f/8.0f, 1.0f/9.0f, 1.0f/10.0f
    };

#pragma unroll
    for (int i = 0; i < N_KPTS; ++i) {
        // c[k] = coeff of x^k in prod_{j != i} (x - kp[j]); all indexing static
        f32x2 c[N_KPTS];
        c[0] = splat2(1.0f);
#pragma unroll
        for (int k = 1; k < N_KPTS; ++k) c[k] = splat2(0.0f);

        f32x2 denom = splat2(1.0f);
#pragma unroll
        for (int j = 0; j < N_KPTS; ++j) {
            if (j == i) continue;                  // elided at compile time
            f32x2 nkpj = -kp[j];
            denom = denom * (kp[i] - kp[j]);
#pragma unroll
            for (int k = N_KPTS - 1; k >= 1; --k)
                c[k] = vfma2(nkpj, c[k], c[k - 1]);
            c[0] = nkpj * c[0];
        }

        f32x2 inv = splat2(1.0f) / denom;
        f32x2 di  = *(const f32x2*)(d_base + (size_t)i * HW);
#pragma unroll
        for (int o = 0; o < N_KPTS; ++o) {
            f32x2 v = c[o] * (inv * splat2(rcp_tab[o]));
            if ((H == 0) ? (o < 5) : (o >= 5))
                *(f32x2*)(cache_base + (size_t)(o * N_KPTS + i) * HW) = v;
            // H==0 needs all coeffs (integral + planes 1-5); H==1 only o>=5.
            if (H == 0 || o >= 5)
                coeffs[o] = vfma2(v, di, coeffs[o]);
        }
    }

    float* oc = out_coeffs + (size_t)b * (N_KPTS + 1) * HW + hw;
    if (H == 0) {
        // integral over [-1,1]: odd o only: 2*coeffs[o]/(o+2)
        f32x2 integral = coeffs[1] * splat2(2.0f / 3.0f);
        integral = vfma2(coeffs[3], splat2(2.0f / 5.0f), integral);
        integral = vfma2(coeffs[5], splat2(2.0f / 7.0f), integral);
        integral = vfma2(coeffs[7], splat2(2.0f / 9.0f), integral);
        integral = vfma2(coeffs[9], splat2(2.0f / 11.0f), integral);

        f32x2 bl = *(const f32x2*)(blurry + (size_t)b * HW + hw);
        f32x2 baseline = (bl * splat2(2.0f) - integral) * splat2(0.5f);

        *(f32x2*)oc = baseline;                          // plane 0
#pragma unroll
        for (int o = 0; o < 5; ++o)                      // planes 1..5
            *(f32x2*)(oc + (size_t)(o + 1) * HW) = coeffs[o];
    } else {
#pragma unroll
        for (int o = 5; o < N_KPTS; ++o)                 // planes 6..10
            *(f32x2*)(oc + (size_t)(o + 1) * HW) = coeffs[o];
    }
}

__global__ __launch_bounds__(256) void curve_integrator_kernel(
    const float* __restrict__ deriv,    // [BS][N_KPTS][HW]
    const float* __restrict__ blurry,   // [BS][1][HW]
    const float* __restrict__ kpts,     // [BS][N_KPTS][HW]
    float* __restrict__ out_coeffs,     // [BS][N_KPTS+1][HW]
    float* __restrict__ out_cache)      // [BS][N_KPTS][N_KPTS][HW]
{
    const int lane = threadIdx.x & 63;
    const int w    = threadIdx.x >> 6;           // wave in block, 0..3
    const int h    = w >> 1;                     // waves 0,1 -> half 0; 2,3 -> half 1
    // pixel-pair index: block covers 128 pairs; waves 0,2 take pairs 0-63,
    // waves 1,3 take pairs 64-127.
    const int pr   = blockIdx.x * 128 + ((w & 1) << 6) + lane;   // < NPIX/2 exactly
    const int p    = pr * 2;
    const int b    = p / HW;                     // HW % 2 == 0 -> pair stays in plane
    const int hw   = p - b * HW;

    if (h == 0)
        curve_body<0>(b, hw, deriv, blurry, kpts, out_coeffs, out_cache);
    else
        curve_body<1>(b, hw, deriv, blurry, kpts, out_coeffs, out_cache);
}

extern "C" void kernel_launch(void* const* d_in, const int* in_sizes, int n_in,
                              void* d_out, int out_size, void* d_ws, size_t ws_size,
                              hipStream_t stream) {
    const float* deriv  = (const float*)d_in[0];
    const float* blurry = (const float*)d_in[1];
    const float* kpts   = (const float*)d_in[2];

    float* out_coeffs = (float*)d_out;                 // BS*(N_KPTS+1)*HW
    float* out_cache  = (float*)d_out + COEFFS_SIZE;   // BS*N_KPTS*N_KPTS*HW

    int threads = 256;
    int blocks  = NPIX / threads;                      // 1350 (each block: 128 pairs x 2 halves)
    curve_integrator_kernel<<<blocks, threads, 0, stream>>>(
        deriv, blurry, kpts, out_coeffs, out_cache);
}

// Round 8
// 32.537 us; speedup vs baseline: 1.1801x; 1.0755x over previous
//
#include <hip/hip_runtime.h>

#define N_KPTS 10
#define BS 8
#define HH 180
#define WW 240
#define HW (HH * WW)
#define NPIX (BS * HW)
#define NT2 (NPIX / 2)                      // 172800 threads, 2 px each
#define COEFFS_SIZE (BS * (N_KPTS + 1) * HW)

typedef float f32x2 __attribute__((ext_vector_type(2)));

static __device__ __forceinline__ f32x2 splat2(float x) { return (f32x2){x, x}; }
static __device__ __forceinline__ f32x2 vfma2(f32x2 a, f32x2 b, f32x2 c) {
    f32x2 r;
    r.x = fmaf(a.x, b.x, c.x);
    r.y = fmaf(a.y, b.y, c.y);
    return r;
}

// R4 structure (f32x2, 2 px/thread, 256-thread blocks, 2700 waves) with the
// Lagrange algebra restructured: build monic P(x) = prod_j (x - kp_j) once
// (~55 FMAs), then each basis numerator c_i = P / (x - kp_i) via synthetic
// division (9 FMAs) instead of a fresh 81-FMA product. Denominators kept as
// direct gap products (Horner of P' near its own root is ~0.3% relative —
// too sloppy; direct subtraction products are exact-ish). ~2.2x fewer VALU
// instructions, much shorter dependent chains at 2.64 waves/SIMD.
__global__ __launch_bounds__(256) void curve_integrator_kernel(
    const float* __restrict__ deriv,    // [BS][N_KPTS][HW]
    const float* __restrict__ blurry,   // [BS][1][HW]
    const float* __restrict__ kpts,     // [BS][N_KPTS][HW]
    float* __restrict__ out_coeffs,     // [BS][N_KPTS+1][HW]
    float* __restrict__ out_cache)      // [BS][N_KPTS][N_KPTS][HW]
{
    int t = blockIdx.x * blockDim.x + threadIdx.x;
    if (t >= NT2) return;
    int p_ = t * 2;                 // first pixel of this thread's pair
    int b  = p_ / HW;               // HW % 2 == 0 -> pair never crosses planes
    int hw = p_ - b * HW;

    const float* kp_base    = kpts  + (size_t)b * N_KPTS * HW + hw;
    const float* d_base     = deriv + (size_t)b * N_KPTS * HW + hw;
    float*       cache_base = out_cache + (size_t)b * N_KPTS * N_KPTS * HW + hw;

    f32x2 kp[N_KPTS];
#pragma unroll
    for (int i = 0; i < N_KPTS; ++i)
        kp[i] = *(const f32x2*)(kp_base + (size_t)i * HW);

    // P(x) = prod_j (x - kp[j]); monic, coefficients p[0..10], p[10] = 1.
    f32x2 p[N_KPTS + 1];
    p[0] = splat2(1.0f);
#pragma unroll
    for (int j = 0; j < N_KPTS; ++j) {
        f32x2 nk = -kp[j];
        p[j + 1] = p[j];                       // new leading coeff (stays 1)
#pragma unroll
        for (int k = N_KPTS; k >= 1; --k) {    // only k<=j holds live data;
            if (k > j) continue;               // pruned at compile time
            p[k] = vfma2(nk, p[k], p[k - 1]);
        }
        p[0] = nk * p[0];
    }

    f32x2 coeffs[N_KPTS];
#pragma unroll
    for (int o = 0; o < N_KPTS; ++o) coeffs[o] = splat2(0.0f);

    const float rcp_tab[N_KPTS] = {
        1.0f, 1.0f/2.0f, 1.0f/3.0f, 1.0f/4.0f, 1.0f/5.0f,
        1.0f/6.0f, 1.0f/7.0f, 1.0f/8.0f, 1.0f/9.0f, 1.0f/10.0f
    };

#pragma unroll
    for (int i = 0; i < N_KPTS; ++i) {
        f32x2 x = kp[i];

        // c_i = P / (x - kp_i) by synthetic division: c[9]=1;
        // c[k-1] = p[k] + x*c[k], k = 9..1.
        f32x2 c[N_KPTS];
        c[N_KPTS - 1] = splat2(1.0f);
#pragma unroll
        for (int k = N_KPTS - 1; k >= 1; --k)
            c[k - 1] = vfma2(x, c[k], p[k]);

        // denom_i = prod_{j != i} (kp_i - kp_j), direct (numerically safe)
        f32x2 denom = splat2(1.0f);
#pragma unroll
        for (int j = 0; j < N_KPTS; ++j) {
            if (j == i) continue;              // elided at compile time
            denom = denom * (x - kp[j]);
        }

        f32x2 inv = splat2(1.0f) / denom;
        f32x2 di  = *(const f32x2*)(d_base + (size_t)i * HW);
#pragma unroll
        for (int o = 0; o < N_KPTS; ++o) {
            f32x2 v = c[o] * (inv * splat2(rcp_tab[o]));
            *(f32x2*)(cache_base + (size_t)(o * N_KPTS + i) * HW) = v;
            coeffs[o] = vfma2(v, di, coeffs[o]);
        }
    }

    // integral over [-1,1]: odd o only: 2*coeffs[o]/(o+2)
    f32x2 integral = coeffs[1] * splat2(2.0f / 3.0f);
    integral = vfma2(coeffs[3], splat2(2.0f / 5.0f), integral);
    integral = vfma2(coeffs[5], splat2(2.0f / 7.0f), integral);
    integral = vfma2(coeffs[7], splat2(2.0f / 9.0f), integral);
    integral = vfma2(coeffs[9], splat2(2.0f / 11.0f), integral);

    f32x2 bl = *(const f32x2*)(blurry + (size_t)b * HW + hw);
    f32x2 baseline = (bl * splat2(2.0f) - integral) * splat2(0.5f);

    float* oc = out_coeffs + (size_t)b * (N_KPTS + 1) * HW + hw;
    *(f32x2*)oc = baseline;
#pragma unroll
    for (int o = 0; o < N_KPTS; ++o)
        *(f32x2*)(oc + (size_t)(o + 1) * HW) = coeffs[o];
}

extern "C" void kernel_launch(void* const* d_in, const int* in_sizes, int n_in,
                              void* d_out, int out_size, void* d_ws, size_t ws_size,
                              hipStream_t stream) {
    const float* deriv  = (const float*)d_in[0];
    const float* blurry = (const float*)d_in[1];
    const float* kpts   = (const float*)d_in[2];

    float* out_coeffs = (float*)d_out;                 // BS*(N_KPTS+1)*HW
    float* out_cache  = (float*)d_out + COEFFS_SIZE;   // BS*N_KPTS*N_KPTS*HW

    int threads = 256;
    int blocks  = (NT2 + threads - 1) / threads;       // 675
    curve_integrator_kernel<<<blocks, threads, 0, stream>>>(
        deriv, blurry, kpts, out_coeffs, out_cache);
}